// Round 8
// baseline (390.471 us; speedup 1.0000x reference)
//
#include <hip/hip_runtime.h>

#define N_NODES 100000
#define N_EDGES 1600000
#define NBUCK 391   // dst buckets of 256 nodes (dst>>8)
#define CHUNKA 8192
#define NBLKA 196   // ceil(N_EDGES/CHUNKA)

typedef __bf16 bf16x8 __attribute__((ext_vector_type(8)));
typedef float f32x4 __attribute__((ext_vector_type(4)));

// fp32 -> bf16 (RNE) as ushort
__device__ inline unsigned short bf1(float a) {
    unsigned u = __builtin_bit_cast(unsigned, a);
    u = (u + 0x7FFF + ((u >> 16) & 1)) >> 16;
    return (unsigned short)u;
}
// pack two fp32 -> two bf16 in one uint (a=low, b=high)
__device__ inline unsigned bfpack(float a, float b) {
    unsigned ua = __builtin_bit_cast(unsigned, a);
    unsigned ub = __builtin_bit_cast(unsigned, b);
    ua = (ua + 0x7FFF + ((ua >> 16) & 1)) >> 16;
    ub = (ub + 0x7FFF + ((ub >> 16) & 1)) >> 16;
    return ua | (ub << 16);
}

// ---------------- bucket histogram (LDS-privatized) ----------------
__global__ __launch_bounds__(256) void bhist_kernel(const int* __restrict__ ei,
                                                    int* __restrict__ bhist) {
    __shared__ int hist[NBUCK];
    const int t = threadIdx.x;
    const int e0 = blockIdx.x * CHUNKA;
    const int n  = min(CHUNKA, N_EDGES - e0);
    for (int i = t; i < NBUCK; i += 256) hist[i] = 0;
    __syncthreads();
    for (int i = t; i < n; i += 256) {
        int dst = ei[N_EDGES + e0 + i];
        atomicAdd(&hist[dst >> 8], 1);
    }
    __syncthreads();
    for (int i = t; i < NBUCK; i += 256)
        if (hist[i]) atomicAdd(&bhist[i], hist[i]);
}

// ---------------- prep: block0 = bucket scan; blocks 1,2 = W transpose+bf16 ----------------
__global__ __launch_bounds__(512) void prep_kernel(const int* __restrict__ bhist,
                                                   int* __restrict__ boffs,
                                                   const float* __restrict__ W1,
                                                   const float* __restrict__ W2,
                                                   unsigned short* __restrict__ Wt1,
                                                   unsigned short* __restrict__ Wt2) {
    const int t = threadIdx.x;
    if (blockIdx.x == 0) {
        __shared__ int s[512];
        int v = (t < NBUCK) ? bhist[t] : 0;
        s[t] = v;
        __syncthreads();
#pragma unroll
        for (int off = 1; off < 512; off <<= 1) {
            int tv = (t >= off) ? s[t - off] : 0;
            __syncthreads();
            s[t] += tv;
            __syncthreads();
        }
        if (t < NBUCK) boffs[t] = s[t] - v;          // exclusive
        if (t == NBUCK - 1) boffs[NBUCK] = s[t];     // total = N_EDGES
    } else if (blockIdx.x == 1) {
        for (int i = t; i < 128 * 128; i += 512) {
            int k = i >> 7, n = i & 127;
            Wt1[n * 128 + k] = bf1(W1[i]);
        }
    } else {
        for (int i = t; i < 128 * 64; i += 512) {
            int k = i >> 6, n = i & 63;
            Wt2[n * 128 + k] = bf1(W2[i]);
        }
    }
}

// ---------------- CSR build pass A: scatter packed (src<<8)|(dst&255) per bucket ----------------
__global__ __launch_bounds__(256) void binA_kernel(const int* __restrict__ ei,
                                                   const int* __restrict__ boffs,
                                                   int* __restrict__ bcur,
                                                   unsigned* __restrict__ epk) {
    __shared__ int hist[NBUCK], base[NBUCK], cur[NBUCK];
    const int t = threadIdx.x;
    const int e0 = blockIdx.x * CHUNKA;
    const int n  = min(CHUNKA, N_EDGES - e0);
    for (int i = t; i < NBUCK; i += 256) hist[i] = 0;
    __syncthreads();
    for (int i = t; i < n; i += 256) {
        int dst = ei[N_EDGES + e0 + i];
        atomicAdd(&hist[dst >> 8], 1);
    }
    __syncthreads();
    for (int i = t; i < NBUCK; i += 256) {
        int h = hist[i];
        base[i] = boffs[i] + (h ? atomicAdd(&bcur[i], h) : 0);
        cur[i]  = 0;
    }
    __syncthreads();
    for (int i = t; i < n; i += 256) {
        int src = ei[e0 + i];
        int dst = ei[N_EDGES + e0 + i];
        int b   = dst >> 8;
        int r   = atomicAdd(&cur[b], 1);
        epk[base[b] + r] = ((unsigned)src << 8) | (unsigned)(dst & 255);
    }
}

// ---------------- CSR build pass B: per-bucket deg/offs/dis + fine sort ----------------
__global__ __launch_bounds__(256) void binB_kernel(const unsigned* __restrict__ epk,
                                                   const int* __restrict__ boffs,
                                                   int* __restrict__ deg,
                                                   float* __restrict__ dis,
                                                   int* __restrict__ offs,
                                                   int* __restrict__ srcn) {
    __shared__ int cnt[256], s[256], loff[256];
    const int b  = blockIdx.x;
    const int t  = threadIdx.x;
    const int n0 = b << 8;
    const int base = boffs[b];
    const int end  = boffs[b + 1];
    cnt[t] = 0;
    __syncthreads();
    for (int e = base + t; e < end; e += 256)
        atomicAdd(&cnt[epk[e] & 255u], 1);
    __syncthreads();
    // exclusive scan of cnt
    int v = cnt[t];
    s[t] = v;
    __syncthreads();
#pragma unroll
    for (int off = 1; off < 256; off <<= 1) {
        int tv = (t >= off) ? s[t - off] : 0;
        __syncthreads();
        s[t] += tv;
        __syncthreads();
    }
    loff[t] = s[t] - v;
    {
        int node = n0 + t;
        if (node < N_NODES) {
            deg[node]  = v;
            dis[node]  = (v > 0) ? rsqrtf((float)v) : 0.0f;
            offs[node] = base + loff[t];
        }
    }
    cnt[t] = 0;   // reuse as cursor
    __syncthreads();
    for (int e = base + t; e < end; e += 256) {
        unsigned p = epk[e];
        int li  = (int)(p & 255u);
        int r   = atomicAdd(&cnt[li], 1);
        srcn[base + loff[li] + r] = (int)(p >> 8);
    }
}

// ---------------- GEMM1 (MFMA): h1b[N,128](bf16) = (x @ W1) * dis[n] ----------------
__global__ __launch_bounds__(256) void gemm1_kernel(const float* __restrict__ x,
                                                    const unsigned short* __restrict__ Wt1,
                                                    const float* __restrict__ dis,
                                                    unsigned short* __restrict__ h1b) {
    __shared__ unsigned short Asm[64][136];  // row stride 272B (16B-aligned), padded
    __shared__ float diss[64];
    const int t = threadIdx.x;
    const int node0 = blockIdx.x * 64;

#pragma unroll
    for (int c = 0; c < 4; ++c) {
        int i = c * 256 + t;            // 0..1023
        int row = i >> 4, ko = (i & 15) * 8;
        int gn = node0 + row;
        float4 v0 = make_float4(0, 0, 0, 0), v1 = v0;
        if (gn < N_NODES) {
            const float* p = x + (size_t)gn * 128 + ko;
            v0 = *(const float4*)p;
            v1 = *(const float4*)(p + 4);
        }
        uint4 o;
        o.x = bfpack(v0.x, v0.y); o.y = bfpack(v0.z, v0.w);
        o.z = bfpack(v1.x, v1.y); o.w = bfpack(v1.z, v1.w);
        *(uint4*)&Asm[row][ko] = o;
    }
    if (t < 64) {
        int gn = node0 + t;
        diss[t] = (gn < N_NODES) ? dis[gn] : 0.0f;
    }
    __syncthreads();

    const int wv = t >> 6, ln = t & 63;
    const int lc = ln & 15, q = ln >> 4;
    const int n0 = wv * 32;

    bf16x8 bfr[2][4];
#pragma unroll
    for (int nt = 0; nt < 2; ++nt)
#pragma unroll
        for (int k = 0; k < 4; ++k)
            bfr[nt][k] = *(const bf16x8*)(Wt1 + (size_t)(n0 + nt * 16 + lc) * 128 + k * 32 + q * 8);

    f32x4 acc[4][2];
#pragma unroll
    for (int m = 0; m < 4; ++m)
#pragma unroll
        for (int nt = 0; nt < 2; ++nt) acc[m][nt] = (f32x4)(0.0f);

#pragma unroll
    for (int k = 0; k < 4; ++k) {
        bf16x8 af[4];
#pragma unroll
        for (int m = 0; m < 4; ++m)
            af[m] = *(const bf16x8*)&Asm[m * 16 + lc][k * 32 + q * 8];
#pragma unroll
        for (int m = 0; m < 4; ++m)
#pragma unroll
            for (int nt = 0; nt < 2; ++nt)
                acc[m][nt] = __builtin_amdgcn_mfma_f32_16x16x32_bf16(af[m], bfr[nt][k], acc[m][nt], 0, 0, 0);
    }

    // C row = m*16 + q*4 + r, col = n0 + nt*16 + lc  [m89/m91 layout]
#pragma unroll
    for (int m = 0; m < 4; ++m)
#pragma unroll
        for (int r = 0; r < 4; ++r) {
            int lr = m * 16 + q * 4 + r;
            int gn = node0 + lr;
            if (gn < N_NODES) {
                float dv = diss[lr];
#pragma unroll
                for (int nt = 0; nt < 2; ++nt)
                    h1b[(size_t)gn * 128 + n0 + nt * 16 + lc] = bf1(acc[m][nt][r] * dv);
            }
        }
}

// ---------------- GEMM2 (MFMA): h2b[N,64](bf16) = (relu(aggb+b1) @ W2) * dis[n] ----------------
__global__ __launch_bounds__(256) void gemm2_kernel(const unsigned short* __restrict__ aggb,
                                                    const float* __restrict__ b1,
                                                    const unsigned short* __restrict__ Wt2,
                                                    const float* __restrict__ dis,
                                                    unsigned short* __restrict__ h2b) {
    __shared__ unsigned short Asm[64][136];
    __shared__ float diss[64];
    const int t = threadIdx.x;
    const int node0 = blockIdx.x * 64;

#pragma unroll
    for (int c = 0; c < 4; ++c) {
        int i = c * 256 + t;            // 0..1023 units of 8 cols
        int row = i >> 4, ko = (i & 15) * 8;
        int gn = node0 + row;
        uint4 o = make_uint4(0, 0, 0, 0);
        if (gn < N_NODES) {
            uint4 r = *(const uint4*)(aggb + (size_t)gn * 128 + ko);
            const float* bp = b1 + ko;
            float f0 = __builtin_bit_cast(float, r.x << 16)         + bp[0];
            float f1 = __builtin_bit_cast(float, r.x & 0xFFFF0000u) + bp[1];
            float f2 = __builtin_bit_cast(float, r.y << 16)         + bp[2];
            float f3 = __builtin_bit_cast(float, r.y & 0xFFFF0000u) + bp[3];
            float f4 = __builtin_bit_cast(float, r.z << 16)         + bp[4];
            float f5 = __builtin_bit_cast(float, r.z & 0xFFFF0000u) + bp[5];
            float f6 = __builtin_bit_cast(float, r.w << 16)         + bp[6];
            float f7 = __builtin_bit_cast(float, r.w & 0xFFFF0000u) + bp[7];
            o.x = bfpack(fmaxf(f0, 0.0f), fmaxf(f1, 0.0f));
            o.y = bfpack(fmaxf(f2, 0.0f), fmaxf(f3, 0.0f));
            o.z = bfpack(fmaxf(f4, 0.0f), fmaxf(f5, 0.0f));
            o.w = bfpack(fmaxf(f6, 0.0f), fmaxf(f7, 0.0f));
        }
        *(uint4*)&Asm[row][ko] = o;
    }
    if (t < 64) {
        int gn = node0 + t;
        diss[t] = (gn < N_NODES) ? dis[gn] : 0.0f;
    }
    __syncthreads();

    const int wv = t >> 6, ln = t & 63;
    const int lc = ln & 15, q = ln >> 4;
    const int n0 = wv * 16;

    bf16x8 bfr[4];
#pragma unroll
    for (int k = 0; k < 4; ++k)
        bfr[k] = *(const bf16x8*)(Wt2 + (size_t)(n0 + lc) * 128 + k * 32 + q * 8);

    f32x4 acc[4];
#pragma unroll
    for (int m = 0; m < 4; ++m) acc[m] = (f32x4)(0.0f);

#pragma unroll
    for (int k = 0; k < 4; ++k) {
        bf16x8 af[4];
#pragma unroll
        for (int m = 0; m < 4; ++m)
            af[m] = *(const bf16x8*)&Asm[m * 16 + lc][k * 32 + q * 8];
#pragma unroll
        for (int m = 0; m < 4; ++m)
            acc[m] = __builtin_amdgcn_mfma_f32_16x16x32_bf16(af[m], bfr[k], acc[m], 0, 0, 0);
    }

#pragma unroll
    for (int m = 0; m < 4; ++m)
#pragma unroll
        for (int r = 0; r < 4; ++r) {
            int lr = m * 16 + q * 4 + r;
            int gn = node0 + lr;
            if (gn < N_NODES) {
                float dv = diss[lr];
                h2b[(size_t)gn * 64 + n0 + lc] = bf1(acc[m][r] * dv);
            }
        }
}

// ---------------- CSR aggregation, width 128 bf16 -> bf16 ----------------
// one wave per node, 2 edges/iter: half-wave per edge, lane loads uint2 (cols 4l..4l+3)
__global__ __launch_bounds__(256) void agg1_kernel(const int* __restrict__ srcn,
                                                   const int* __restrict__ offs,
                                                   const int* __restrict__ deg,
                                                   const float* __restrict__ dis,
                                                   const unsigned* __restrict__ h1b,
                                                   unsigned* __restrict__ aggb) {
    int wave = (blockIdx.x * 256 + threadIdx.x) >> 6;
    int lane = threadIdx.x & 63;
    if (wave >= N_NODES) return;
    int lh   = lane & 31;
    int half = lane >> 5;
    int beg = offs[wave];
    int d   = deg[wave];
    float dv = dis[wave];
    float a0 = 0.0f, a1 = 0.0f, a2 = 0.0f, a3 = 0.0f;
#pragma unroll 2
    for (int k = 0; k < d; k += 2) {
        int kk = k + half;
        if (kk < d) {
            int src = srcn[beg + kk];
            uint2 v = *(const uint2*)(h1b + (size_t)src * 64 + lh * 2);
            a0 += __builtin_bit_cast(float, v.x << 16);
            a1 += __builtin_bit_cast(float, v.x & 0xFFFF0000u);
            a2 += __builtin_bit_cast(float, v.y << 16);
            a3 += __builtin_bit_cast(float, v.y & 0xFFFF0000u);
        }
    }
    a0 += __shfl_xor(a0, 32);
    a1 += __shfl_xor(a1, 32);
    a2 += __shfl_xor(a2, 32);
    a3 += __shfl_xor(a3, 32);
    if (half == 0) {
        uint2 o;
        o.x = bfpack(dv * a0, dv * a1);
        o.y = bfpack(dv * a2, dv * a3);
        *(uint2*)(aggb + (size_t)wave * 64 + lh * 2) = o;
    }
}

// ---------------- CSR aggregation, width 64 bf16, + b2 -> out ----------------
// one wave per node, 2 edges/iter: half-wave per edge, lane loads uint (cols 2l,2l+1)
__global__ __launch_bounds__(256) void agg2_kernel(const int* __restrict__ srcn,
                                                   const int* __restrict__ offs,
                                                   const int* __restrict__ deg,
                                                   const float* __restrict__ dis,
                                                   const unsigned* __restrict__ h2b,
                                                   const float* __restrict__ b2,
                                                   float* __restrict__ out) {
    int wave = (blockIdx.x * 256 + threadIdx.x) >> 6;
    int lane = threadIdx.x & 63;
    if (wave >= N_NODES) return;
    int lh   = lane & 31;
    int half = lane >> 5;
    int beg = offs[wave];
    int d   = deg[wave];
    float dv = dis[wave];
    float ax = 0.0f, ay = 0.0f;
#pragma unroll 2
    for (int k = 0; k < d; k += 2) {
        int kk = k + half;
        if (kk < d) {
            int src = srcn[beg + kk];
            unsigned v = h2b[(size_t)src * 32 + lh];
            ax += __builtin_bit_cast(float, v << 16);
            ay += __builtin_bit_cast(float, v & 0xFFFF0000u);
        }
    }
    ax += __shfl_xor(ax, 32);
    ay += __shfl_xor(ay, 32);
    if (half == 0) {
        float2 bb = *(const float2*)(b2 + lh * 2);
        float2 o = make_float2(dv * ax + bb.x, dv * ay + bb.y);
        *(float2*)(out + (size_t)wave * 64 + lh * 2) = o;
    }
}

extern "C" void kernel_launch(void* const* d_in, const int* in_sizes, int n_in,
                              void* d_out, int out_size, void* d_ws, size_t ws_size,
                              hipStream_t stream) {
    const float* x  = (const float*)d_in[0];
    const int*   ei = (const int*)d_in[1];
    const float* W1 = (const float*)d_in[2];
    const float* b1 = (const float*)d_in[3];
    const float* W2 = (const float*)d_in[4];
    const float* b2 = (const float*)d_in[5];
    float* out = (float*)d_out;

    char* ws = (char*)d_ws;
    int*   bhist = (int*)(ws);                           // 1.6 KB  @ 0
    int*   bcur  = (int*)(ws + (size_t)4 * 1024);        // 1.6 KB  @ 4 KB
    int*   boffs = (int*)(ws + (size_t)8 * 1024);        // 1.6 KB  @ 8 KB
    int*   deg   = (int*)(ws + (size_t)16 * 1024);       // 400 KB  @ 16 KB
    int*   offs  = (int*)(ws + (size_t)512 * 1024);      // 400 KB  @ 512 KB
    float* dis   = (float*)(ws + (size_t)1024 * 1024);   // 400 KB  @ 1 MB
    unsigned short* Wt1 = (unsigned short*)(ws + (size_t)1536 * 1024);  // 32 KB @ 1.5 MB
    unsigned short* Wt2 = (unsigned short*)(ws + (size_t)1600 * 1024);  // 16 KB
    unsigned* epk = (unsigned*)(ws + (size_t)2560 * 1024);   // 6.4 MB @ 2.5 MB
    int*   srcn  = (int*)(ws + (size_t)9216 * 1024);     // 6.4 MB  @ 9 MB
    unsigned short* h1b = (unsigned short*)(ws + (size_t)16 * 1024 * 1024);  // 25.6 MB @ 16 MB
    unsigned short* h2b = h1b;                            // 12.8 MB, aliases h1b (dead by then)
    unsigned short* aggb = (unsigned short*)(ws + (size_t)48 * 1024 * 1024); // 25.6 MB @ 48 MB

    hipMemsetAsync(ws, 0, (size_t)8 * 1024, stream);  // bhist + bcur

    bhist_kernel<<<NBLKA, 256, 0, stream>>>(ei, bhist);
    prep_kernel<<<3, 512, 0, stream>>>(bhist, boffs, W1, W2, Wt1, Wt2);
    binA_kernel<<<NBLKA, 256, 0, stream>>>(ei, boffs, bcur, epk);
    binB_kernel<<<NBUCK, 256, 0, stream>>>(epk, boffs, deg, dis, offs, srcn);
    gemm1_kernel<<<(N_NODES + 63) / 64, 256, 0, stream>>>(x, Wt1, dis, h1b);
    agg1_kernel<<<(N_NODES * 64 + 255) / 256, 256, 0, stream>>>(srcn, offs, deg, dis,
                                                                (const unsigned*)h1b,
                                                                (unsigned*)aggb);
    gemm2_kernel<<<(N_NODES + 63) / 64, 256, 0, stream>>>(aggb, b1, Wt2, dis, h2b);
    agg2_kernel<<<(N_NODES * 64 + 255) / 256, 256, 0, stream>>>(srcn, offs, deg, dis,
                                                                (const unsigned*)h2b, b2, out);
}

// Round 9
// 320.165 us; speedup vs baseline: 1.2196x; 1.2196x over previous
//
#include <hip/hip_runtime.h>

#define N_NODES 100000
#define N_EDGES 1600000
#define NBUCK 391   // dst buckets of 256 nodes (dst>>8)
#define CHUNKA 8192
#define NBLKA 196   // ceil(N_EDGES/CHUNKA)

typedef __bf16 bf16x8 __attribute__((ext_vector_type(8)));
typedef float f32x4 __attribute__((ext_vector_type(4)));

// fp32 -> bf16 (RNE) as ushort
__device__ inline unsigned short bf1(float a) {
    unsigned u = __builtin_bit_cast(unsigned, a);
    u = (u + 0x7FFF + ((u >> 16) & 1)) >> 16;
    return (unsigned short)u;
}
// pack two fp32 -> two bf16 in one uint (a=low, b=high)
__device__ inline unsigned bfpack(float a, float b) {
    unsigned ua = __builtin_bit_cast(unsigned, a);
    unsigned ub = __builtin_bit_cast(unsigned, b);
    ua = (ua + 0x7FFF + ((ua >> 16) & 1)) >> 16;
    ub = (ub + 0x7FFF + ((ub >> 16) & 1)) >> 16;
    return ua | (ub << 16);
}
__device__ inline float bf2f(unsigned short u) {
    return __builtin_bit_cast(float, ((unsigned)u) << 16);
}

// ---------------- bucket histogram (LDS-privatized) ----------------
__global__ __launch_bounds__(256) void bhist_kernel(const int* __restrict__ ei,
                                                    int* __restrict__ bhist) {
    __shared__ int hist[NBUCK];
    const int t = threadIdx.x;
    const int e0 = blockIdx.x * CHUNKA;
    const int n  = min(CHUNKA, N_EDGES - e0);
    for (int i = t; i < NBUCK; i += 256) hist[i] = 0;
    __syncthreads();
    for (int i = t; i < n; i += 256) {
        int dst = ei[N_EDGES + e0 + i];
        atomicAdd(&hist[dst >> 8], 1);
    }
    __syncthreads();
    for (int i = t; i < NBUCK; i += 256)
        if (hist[i]) atomicAdd(&bhist[i], hist[i]);
}

// ---------------- prep: block0 = bucket scan; blocks 1,2 = W transpose+bf16 ----------------
__global__ __launch_bounds__(512) void prep_kernel(const int* __restrict__ bhist,
                                                   int* __restrict__ boffs,
                                                   const float* __restrict__ W1,
                                                   const float* __restrict__ W2,
                                                   unsigned short* __restrict__ Wt1,
                                                   unsigned short* __restrict__ Wt2) {
    const int t = threadIdx.x;
    if (blockIdx.x == 0) {
        __shared__ int s[512];
        int v = (t < NBUCK) ? bhist[t] : 0;
        s[t] = v;
        __syncthreads();
#pragma unroll
        for (int off = 1; off < 512; off <<= 1) {
            int tv = (t >= off) ? s[t - off] : 0;
            __syncthreads();
            s[t] += tv;
            __syncthreads();
        }
        if (t < NBUCK) boffs[t] = s[t] - v;          // exclusive
        if (t == NBUCK - 1) boffs[NBUCK] = s[t];     // total = N_EDGES
    } else if (blockIdx.x == 1) {
        for (int i = t; i < 128 * 128; i += 512) {
            int k = i >> 7, n = i & 127;
            Wt1[n * 128 + k] = bf1(W1[i]);
        }
    } else {
        for (int i = t; i < 128 * 64; i += 512) {
            int k = i >> 6, n = i & 63;
            Wt2[n * 128 + k] = bf1(W2[i]);
        }
    }
}

// ---------------- CSR build pass A: scatter packed (src<<8)|(dst&255) per bucket ----------------
__global__ __launch_bounds__(256) void binA_kernel(const int* __restrict__ ei,
                                                   const int* __restrict__ boffs,
                                                   int* __restrict__ bcur,
                                                   unsigned* __restrict__ epk) {
    __shared__ int hist[NBUCK], base[NBUCK], cur[NBUCK];
    const int t = threadIdx.x;
    const int e0 = blockIdx.x * CHUNKA;
    const int n  = min(CHUNKA, N_EDGES - e0);
    for (int i = t; i < NBUCK; i += 256) hist[i] = 0;
    __syncthreads();
    for (int i = t; i < n; i += 256) {
        int dst = ei[N_EDGES + e0 + i];
        atomicAdd(&hist[dst >> 8], 1);
    }
    __syncthreads();
    for (int i = t; i < NBUCK; i += 256) {
        int h = hist[i];
        base[i] = boffs[i] + (h ? atomicAdd(&bcur[i], h) : 0);
        cur[i]  = 0;
    }
    __syncthreads();
    for (int i = t; i < n; i += 256) {
        int src = ei[e0 + i];
        int dst = ei[N_EDGES + e0 + i];
        int b   = dst >> 8;
        int r   = atomicAdd(&cur[b], 1);
        epk[base[b] + r] = ((unsigned)src << 8) | (unsigned)(dst & 255);
    }
}

// ---------------- CSR build pass B: per-bucket deg/offs/dis + fine sort ----------------
__global__ __launch_bounds__(256) void binB_kernel(const unsigned* __restrict__ epk,
                                                   const int* __restrict__ boffs,
                                                   int* __restrict__ deg,
                                                   float* __restrict__ dis,
                                                   int* __restrict__ offs,
                                                   int* __restrict__ srcn) {
    __shared__ int cnt[256], s[256], loff[256];
    const int b  = blockIdx.x;
    const int t  = threadIdx.x;
    const int n0 = b << 8;
    const int base = boffs[b];
    const int end  = boffs[b + 1];
    cnt[t] = 0;
    __syncthreads();
    for (int e = base + t; e < end; e += 256)
        atomicAdd(&cnt[epk[e] & 255u], 1);
    __syncthreads();
    // exclusive scan of cnt
    int v = cnt[t];
    s[t] = v;
    __syncthreads();
#pragma unroll
    for (int off = 1; off < 256; off <<= 1) {
        int tv = (t >= off) ? s[t - off] : 0;
        __syncthreads();
        s[t] += tv;
        __syncthreads();
    }
    loff[t] = s[t] - v;
    {
        int node = n0 + t;
        if (node < N_NODES) {
            deg[node]  = v;
            dis[node]  = (v > 0) ? rsqrtf((float)v) : 0.0f;
            offs[node] = base + loff[t];
        }
    }
    cnt[t] = 0;   // reuse as cursor
    __syncthreads();
    for (int e = base + t; e < end; e += 256) {
        unsigned p = epk[e];
        int li  = (int)(p & 255u);
        int r   = atomicAdd(&cnt[li], 1);
        srcn[base + loff[li] + r] = (int)(p >> 8);
    }
}

// ---------------- GEMM1 (MFMA): h1b[N,128](bf16) = (x @ W1) * dis[n] ----------------
__global__ __launch_bounds__(256) void gemm1_kernel(const float* __restrict__ x,
                                                    const unsigned short* __restrict__ Wt1,
                                                    const float* __restrict__ dis,
                                                    unsigned short* __restrict__ h1b) {
    __shared__ unsigned short Asm[64][136];  // row stride 272B (16B-aligned), padded
    __shared__ float diss[64];
    const int t = threadIdx.x;
    const int node0 = blockIdx.x * 64;

#pragma unroll
    for (int c = 0; c < 4; ++c) {
        int i = c * 256 + t;            // 0..1023
        int row = i >> 4, ko = (i & 15) * 8;
        int gn = node0 + row;
        float4 v0 = make_float4(0, 0, 0, 0), v1 = v0;
        if (gn < N_NODES) {
            const float* p = x + (size_t)gn * 128 + ko;
            v0 = *(const float4*)p;
            v1 = *(const float4*)(p + 4);
        }
        uint4 o;
        o.x = bfpack(v0.x, v0.y); o.y = bfpack(v0.z, v0.w);
        o.z = bfpack(v1.x, v1.y); o.w = bfpack(v1.z, v1.w);
        *(uint4*)&Asm[row][ko] = o;
    }
    if (t < 64) {
        int gn = node0 + t;
        diss[t] = (gn < N_NODES) ? dis[gn] : 0.0f;
    }
    __syncthreads();

    const int wv = t >> 6, ln = t & 63;
    const int lc = ln & 15, q = ln >> 4;
    const int n0 = wv * 32;

    bf16x8 bfr[2][4];
#pragma unroll
    for (int nt = 0; nt < 2; ++nt)
#pragma unroll
        for (int k = 0; k < 4; ++k)
            bfr[nt][k] = *(const bf16x8*)(Wt1 + (size_t)(n0 + nt * 16 + lc) * 128 + k * 32 + q * 8);

    f32x4 acc[4][2];
#pragma unroll
    for (int m = 0; m < 4; ++m)
#pragma unroll
        for (int nt = 0; nt < 2; ++nt) acc[m][nt] = (f32x4)(0.0f);

#pragma unroll
    for (int k = 0; k < 4; ++k) {
        bf16x8 af[4];
#pragma unroll
        for (int m = 0; m < 4; ++m)
            af[m] = *(const bf16x8*)&Asm[m * 16 + lc][k * 32 + q * 8];
#pragma unroll
        for (int m = 0; m < 4; ++m)
#pragma unroll
            for (int nt = 0; nt < 2; ++nt)
                acc[m][nt] = __builtin_amdgcn_mfma_f32_16x16x32_bf16(af[m], bfr[nt][k], acc[m][nt], 0, 0, 0);
    }

    // C row = m*16 + q*4 + r, col = n0 + nt*16 + lc  [m89/m91 layout]
#pragma unroll
    for (int m = 0; m < 4; ++m)
#pragma unroll
        for (int r = 0; r < 4; ++r) {
            int lr = m * 16 + q * 4 + r;
            int gn = node0 + lr;
            if (gn < N_NODES) {
                float dv = diss[lr];
#pragma unroll
                for (int nt = 0; nt < 2; ++nt)
                    h1b[(size_t)gn * 128 + n0 + nt * 16 + lc] = bf1(acc[m][nt][r] * dv);
            }
        }
}

// ---------------- FUSED agg1 + GEMM2 ----------------
// block = 64 dst nodes. Phase 1: full-wave gather per node (R6 agg1 pattern),
// z = relu(dis*Σ + b1) -> bf16 LDS. Phase 2: MFMA z @ W2t, * dis, -> h2b.
__global__ __launch_bounds__(256) void agg1gemm2_kernel(const int* __restrict__ srcn,
                                                        const int* __restrict__ offs,
                                                        const int* __restrict__ deg,
                                                        const float* __restrict__ dis,
                                                        const unsigned* __restrict__ h1b,
                                                        const float* __restrict__ b1,
                                                        const unsigned short* __restrict__ Wt2,
                                                        unsigned short* __restrict__ h2b) {
    __shared__ unsigned short Zs[64][136];  // z rows, bf16, padded (272B stride)
    __shared__ float diss[64];
    __shared__ int offs_s[64], deg_s[64];
    const int t = threadIdx.x;
    const int node0 = blockIdx.x * 64;
    if (t < 64) {
        int gn = node0 + t;
        bool ok = gn < N_NODES;
        offs_s[t] = ok ? offs[gn] : 0;
        deg_s[t]  = ok ? deg[gn] : 0;
        diss[t]   = ok ? dis[gn] : 0.0f;
    }
    __syncthreads();

    const int wv = t >> 6, ln = t & 63;
    float2 bb = *(const float2*)(b1 + ln * 2);

    // Phase 1: wave wv aggregates nodes wv*16 .. wv*16+15 (lane = col pair)
    for (int i = 0; i < 16; ++i) {
        int lr  = wv * 16 + i;
        int beg = offs_s[lr];
        int d   = deg_s[lr];
        float dv = diss[lr];
        float ax = 0.0f, ay = 0.0f;
#pragma unroll 4
        for (int k = 0; k < d; ++k) {
            int src = srcn[beg + k];
            unsigned v = h1b[(size_t)src * 64 + ln];
            ax += __builtin_bit_cast(float, v << 16);
            ay += __builtin_bit_cast(float, v & 0xFFFF0000u);
        }
        float z0 = fmaxf(dv * ax + bb.x, 0.0f);
        float z1 = fmaxf(dv * ay + bb.y, 0.0f);
        *(unsigned*)&Zs[lr][ln * 2] = bfpack(z0, z1);
    }
    __syncthreads();

    // Phase 2: MFMA (identical structure to verified gemm2)
    const int lc = ln & 15, q = ln >> 4;
    const int n0 = wv * 16;

    bf16x8 bfr[4];
#pragma unroll
    for (int k = 0; k < 4; ++k)
        bfr[k] = *(const bf16x8*)(Wt2 + (size_t)(n0 + lc) * 128 + k * 32 + q * 8);

    f32x4 acc[4];
#pragma unroll
    for (int m = 0; m < 4; ++m) acc[m] = (f32x4)(0.0f);

#pragma unroll
    for (int k = 0; k < 4; ++k) {
        bf16x8 af[4];
#pragma unroll
        for (int m = 0; m < 4; ++m)
            af[m] = *(const bf16x8*)&Zs[m * 16 + lc][k * 32 + q * 8];
#pragma unroll
        for (int m = 0; m < 4; ++m)
            acc[m] = __builtin_amdgcn_mfma_f32_16x16x32_bf16(af[m], bfr[k], acc[m], 0, 0, 0);
    }

#pragma unroll
    for (int m = 0; m < 4; ++m)
#pragma unroll
        for (int r = 0; r < 4; ++r) {
            int lr = m * 16 + q * 4 + r;
            int gn = node0 + lr;
            if (gn < N_NODES) {
                float dv = diss[lr];
                h2b[(size_t)gn * 64 + n0 + lc] = bf1(acc[m][r] * dv);
            }
        }
}

// ---------------- CSR aggregation, width 64 bf16, + b2 -> out (R6 form) ----------------
__global__ __launch_bounds__(256) void agg2_kernel(const int* __restrict__ srcn,
                                                   const int* __restrict__ offs,
                                                   const int* __restrict__ deg,
                                                   const float* __restrict__ dis,
                                                   const unsigned short* __restrict__ h2b,
                                                   const float* __restrict__ b2,
                                                   float* __restrict__ out) {
    int wave = (blockIdx.x * 256 + threadIdx.x) >> 6;
    int lane = threadIdx.x & 63;
    if (wave >= N_NODES) return;
    int beg = offs[wave];
    int d   = deg[wave];
    float dv = dis[wave];
    float acc = 0.0f;
#pragma unroll 4
    for (int k = 0; k < d; ++k) {
        int src = srcn[beg + k];
        acc += bf2f(h2b[(size_t)src * 64 + lane]);
    }
    out[(size_t)wave * 64 + lane] = dv * acc + b2[lane];
}

extern "C" void kernel_launch(void* const* d_in, const int* in_sizes, int n_in,
                              void* d_out, int out_size, void* d_ws, size_t ws_size,
                              hipStream_t stream) {
    const float* x  = (const float*)d_in[0];
    const int*   ei = (const int*)d_in[1];
    const float* W1 = (const float*)d_in[2];
    const float* b1 = (const float*)d_in[3];
    const float* W2 = (const float*)d_in[4];
    const float* b2 = (const float*)d_in[5];
    float* out = (float*)d_out;

    char* ws = (char*)d_ws;
    int*   bhist = (int*)(ws);                           // 1.6 KB  @ 0
    int*   bcur  = (int*)(ws + (size_t)4 * 1024);        // 1.6 KB  @ 4 KB
    int*   boffs = (int*)(ws + (size_t)8 * 1024);        // 1.6 KB  @ 8 KB
    int*   deg   = (int*)(ws + (size_t)16 * 1024);       // 400 KB  @ 16 KB
    int*   offs  = (int*)(ws + (size_t)512 * 1024);      // 400 KB  @ 512 KB
    float* dis   = (float*)(ws + (size_t)1024 * 1024);   // 400 KB  @ 1 MB
    unsigned short* Wt1 = (unsigned short*)(ws + (size_t)1536 * 1024);  // 32 KB @ 1.5 MB
    unsigned short* Wt2 = (unsigned short*)(ws + (size_t)1600 * 1024);  // 16 KB
    unsigned* epk = (unsigned*)(ws + (size_t)2560 * 1024);   // 6.4 MB @ 2.5 MB
    int*   srcn  = (int*)(ws + (size_t)9216 * 1024);     // 6.4 MB  @ 9 MB
    unsigned short* h1b = (unsigned short*)(ws + (size_t)16 * 1024 * 1024);  // 25.6 MB @ 16 MB
    unsigned short* h2b = (unsigned short*)(ws + (size_t)48 * 1024 * 1024); // 12.8 MB @ 48 MB

    hipMemsetAsync(ws, 0, (size_t)8 * 1024, stream);  // bhist + bcur

    bhist_kernel<<<NBLKA, 256, 0, stream>>>(ei, bhist);
    prep_kernel<<<3, 512, 0, stream>>>(bhist, boffs, W1, W2, Wt1, Wt2);
    binA_kernel<<<NBLKA, 256, 0, stream>>>(ei, boffs, bcur, epk);
    binB_kernel<<<NBUCK, 256, 0, stream>>>(epk, boffs, deg, dis, offs, srcn);
    gemm1_kernel<<<(N_NODES + 63) / 64, 256, 0, stream>>>(x, Wt1, dis, h1b);
    agg1gemm2_kernel<<<(N_NODES + 63) / 64, 256, 0, stream>>>(srcn, offs, deg, dis,
                                                              (const unsigned*)h1b, b1, Wt2, h2b);
    agg2_kernel<<<(N_NODES * 64 + 255) / 256, 256, 0, stream>>>(srcn, offs, deg, dis, h2b, b2, out);
}